// Round 14
// baseline (323.018 us; speedup 1.0000x reference)
//
#include <hip/hip_runtime.h>
#include <math.h>

#define Tt  30
#define INP 32
#define HID 64
#define NEG 0.2f
#define P   72      // h pitch in halfs: row stride 144B -> ds_read_b128 2-way banks (free)
#define CAP 64      // fixed bucket capacity per dst (P(deg>64) ~ 1e-20 for Poisson(16)+self)
#define LOG2E  1.4426950408889634f
#define N2LOG2E (-2.885390081777927f)

typedef __attribute__((ext_vector_type(8))) _Float16 half8;
typedef __attribute__((ext_vector_type(2))) __fp16   fp16x2;   // builtin-compatible f16 pair
typedef __attribute__((ext_vector_type(4))) float    f4;

#define MFMA16(a,b,c) __builtin_amdgcn_mfma_f32_16x16x32_f16((a),(b),(c),0,0,0)

__device__ __forceinline__ float f16lo(unsigned u){
    union{unsigned short s; _Float16 f;} c; c.s = (unsigned short)(u & 0xffffu); return (float)c.f;
}
__device__ __forceinline__ float f16hi(unsigned u){
    union{unsigned short s; _Float16 f;} c; c.s = (unsigned short)(u >> 16); return (float)c.f;
}
__device__ __forceinline__ fp16x2 u2h2(unsigned u){
    union{unsigned u; fp16x2 h;} c; c.u = u; return c.h;
}

// B fragment (single f16, optionally pre-scaled): k = kt*32 + quad*8 + e, col fixed per lane
__device__ __forceinline__ void loadW(const float* __restrict__ Wa, const float* __restrict__ Wb,
                                      int R0, int kt, int quad, int col, float scale, half8& H){
    #pragma unroll
    for (int e = 0; e < 8; ++e){
        int r = kt*32 + quad*8 + e;
        float v = (r < R0) ? Wa[r*256 + col] : Wb[(r - R0)*256 + col];
        H[e] = (_Float16)(v * scale);
    }
}

// ====== FUSED 2-layer LSTM (native f16, 1 barrier/timestep) + GAT1 projection tail ======
// Gate weights pre-scaled by -log2e (i,f,o) / -2log2e (g) -> raw exp2 in epilogue.
// Epilogue uses PAIRED reciprocals: rcp(d0*d1) recovers both inverses with 3 muls,
// halving the quarter-rate trans-pipe rcp count (40 -> 20 per thread-step).
__global__ __launch_bounds__(256, 2) void k_lstm_fused(
    const float* __restrict__ x,
    const float* __restrict__ Wih0, const float* __restrict__ Whh0,
    const float* __restrict__ bih0, const float* __restrict__ bhh0,
    const float* __restrict__ Wih1, const float* __restrict__ Whh1,
    const float* __restrict__ bih1, const float* __restrict__ bhh1,
    const float* __restrict__ W1,  const float* __restrict__ as1,
    const float* __restrict__ ad1,
    _Float16* __restrict__ H1, float* __restrict__ a_s, float* __restrict__ a_d,
    int* __restrict__ deg)
{
    __shared__ _Float16 sH0[2][16 * P];   // 4.6 KB
    __shared__ _Float16 sH1[2][16 * P];   // 4.6 KB

    const int tid = threadIdx.x, lane = tid & 63, j = tid >> 6;
    const int quad = lane >> 4, ln = lane & 15;
    const int jc = j * 16 + ln;           // hidden col this thread epilogues
    const int n0 = blockIdx.x * 16;

    if (tid < 16) deg[n0 + tid] = 0;      // replaces hipMemsetAsync (k_fill runs after us)

    const float sc[4] = { -LOG2E, -LOG2E, N2LOG2E, -LOG2E };   // i, f, g, o

    // ---- L0 weights: 12 half8 (48 VGPR). K=96: kt0 = x (Wih0), kt1/2 = h0 (Whh0) ----
    half8 w0[3][4];
    #pragma unroll
    for (int kt = 0; kt < 3; ++kt)
        #pragma unroll
        for (int g = 0; g < 4; ++g)
            loadW(Wih0, Whh0, 32, kt, quad, g*64 + jc, sc[g], w0[kt][g]);

    // ---- L1 weights: 16 half8 (64 VGPR). K=128: kt0/1 = h0 (Wih1), kt2/3 = h1 (Whh1) ----
    half8 w1[4][4];
    #pragma unroll
    for (int kt = 0; kt < 4; ++kt)
        #pragma unroll
        for (int g = 0; g < 4; ++g)
            loadW(Wih1, Whh1, 64, kt, quad, g*64 + jc, sc[g], w1[kt][g]);

    float b0[4], b1v[4];
    #pragma unroll
    for (int g = 0; g < 4; ++g){
        b0[g]  = (bih0[g*64 + jc] + bhh0[g*64 + jc]) * sc[g];
        b1v[g] = (bih1[g*64 + jc] + bhh1[g*64 + jc]) * sc[g];
    }

    float c0[4] = {0.f,0.f,0.f,0.f};
    float c1[4] = {0.f,0.f,0.f,0.f};

    for (int idx = tid; idx < 16*P; idx += 256){
        sH0[0][idx] = (_Float16)0.f; sH1[0][idx] = (_Float16)0.f;
    }
    __syncthreads();

    const float* xrow = x + (size_t)(n0 + ln) * (Tt*INP) + quad*8;
    float4 nxa = *(const float4*)xrow, nxb = *(const float4*)(xrow + 4);

    // Paired-rcp LSTM epilogue for 4 rows: acc[g][r] pre-scaled so exp2 gives
    // e^-x (i,f,o) / e^-2x (g). sigmoid = inv(1+e), tanh = 2*inv(1+e)-1.
    #define EPI(acc, cc, dst, PITCHBASE)                                          \
    {                                                                             \
        float ovs[4], dc[4];                                                      \
        _Pragma("unroll")                                                         \
        for (int r = 0; r < 4; ++r){                                              \
            float e0 = __builtin_amdgcn_exp2f(acc[0][r]);                         \
            float e1 = __builtin_amdgcn_exp2f(acc[1][r]);                         \
            float e2 = __builtin_amdgcn_exp2f(acc[2][r]);                         \
            float e3 = __builtin_amdgcn_exp2f(acc[3][r]);                         \
            float d0 = 1.f+e0, d1 = 1.f+e1, d2 = 1.f+e2, d3 = 1.f+e3;             \
            float r01 = __builtin_amdgcn_rcpf(d0*d1);                             \
            float r23 = __builtin_amdgcn_rcpf(d2*d3);                             \
            float iv = r01*d1, fv = r01*d0;                                       \
            float gv = 2.f*(r23*d3) - 1.f;                                        \
            ovs[r] = r23*d2;                                                      \
            cc[r] = fv*cc[r] + iv*gv;                                             \
            dc[r] = 1.f + __builtin_amdgcn_exp2f(cc[r]*N2LOG2E);                  \
        }                                                                         \
        float s01 = __builtin_amdgcn_rcpf(dc[0]*dc[1]);                           \
        float s23 = __builtin_amdgcn_rcpf(dc[2]*dc[3]);                           \
        dst[(PITCHBASE + 0)*P + jc] = (_Float16)(ovs[0]*(2.f*(s01*dc[1]) - 1.f)); \
        dst[(PITCHBASE + 1)*P + jc] = (_Float16)(ovs[1]*(2.f*(s01*dc[0]) - 1.f)); \
        dst[(PITCHBASE + 2)*P + jc] = (_Float16)(ovs[2]*(2.f*(s23*dc[3]) - 1.f)); \
        dst[(PITCHBASE + 3)*P + jc] = (_Float16)(ovs[3]*(2.f*(s23*dc[2]) - 1.f)); \
    }

    #pragma unroll 1
    for (int t = 0; t < Tt; ++t){
        const int pb = t & 1;
        _Float16* h0r = sH0[pb];
        _Float16* h0w = sH0[pb ^ 1];
        _Float16* h1r = sH1[pb];
        _Float16* h1w = sH1[pb ^ 1];

        float4 xa = nxa, xb = nxb;
        if (t + 1 < Tt){
            nxa = *(const float4*)(xrow + (t+1)*INP);
            nxb = *(const float4*)(xrow + (t+1)*INP + 4);
        }
        half8 xf;
        xf[0]=(_Float16)xa.x; xf[1]=(_Float16)xa.y; xf[2]=(_Float16)xa.z; xf[3]=(_Float16)xa.w;
        xf[4]=(_Float16)xb.x; xf[5]=(_Float16)xb.y; xf[6]=(_Float16)xb.z; xf[7]=(_Float16)xb.w;

        // ---- L0 ----
        half8 h0a = *(const half8*)(h0r + ln*P + quad*8);
        half8 h0b = *(const half8*)(h0r + ln*P + 32 + quad*8);
        {
            f4 acc[4];
            #pragma unroll
            for (int g = 0; g < 4; ++g){
                f4 a = {b0[g], b0[g], b0[g], b0[g]};
                a = MFMA16(xf,  w0[0][g], a);
                a = MFMA16(h0a, w0[1][g], a);
                a = MFMA16(h0b, w0[2][g], a);
                acc[g] = a;
            }
            EPI(acc, c0, h0w, quad*4)
        }
        __syncthreads();   // the ONLY barrier in the t-loop

        // ---- L1 ----
        half8 a0 = *(const half8*)(h0w + ln*P + quad*8);
        half8 a1 = *(const half8*)(h0w + ln*P + 32 + quad*8);
        half8 a2 = *(const half8*)(h1r + ln*P + quad*8);
        half8 a3 = *(const half8*)(h1r + ln*P + 32 + quad*8);
        {
            f4 acc[4];
            #pragma unroll
            for (int g = 0; g < 4; ++g){
                f4 a = {b1v[g], b1v[g], b1v[g], b1v[g]};
                a = MFMA16(a0, w1[0][g], a);
                a = MFMA16(a1, w1[1][g], a);
                a = MFMA16(a2, w1[2][g], a);
                a = MFMA16(a3, w1[3][g], a);
                acc[g] = a;
            }
            EPI(acc, c1, h1w, quad*4)
        }
    }
    #undef EPI

    // ---- fused GAT1 projection: H1 = h1·W1 (f16 out) + a_s/a_d (pre-scaled by log2e) ----
    __syncthreads();                      // all waves' final h1 (sH1[0]) visible
    const unsigned* h1u = (const unsigned*)sH1[0];   // f16 pairs, row pitch P/2 uints
    {
        float acc[16];
        #pragma unroll
        for (int r = 0; r < 16; ++r) acc[r] = 0.f;
        for (int jj = 0; jj < 64; jj += 2){
            fp16x2 wpk = __builtin_amdgcn_cvt_pkrtz(W1[jj * 256 + tid], W1[(jj + 1) * 256 + tid]);
            #pragma unroll
            for (int r = 0; r < 16; ++r){
                fp16x2 hv = u2h2(h1u[r * (P/2) + (jj >> 1)]);
                acc[r] = __builtin_amdgcn_fdot2(hv, wpk, acc[r], false);
            }
        }
        const float asv = as1[tid], adv = ad1[tid];
        #pragma unroll
        for (int r = 0; r < 16; ++r){
            H1[(size_t)(n0 + r) * 256 + tid] = (_Float16)acc[r];
            float ls = acc[r] * asv, ld = acc[r] * adv;
            #pragma unroll
            for (int off = 32; off >= 1; off >>= 1){ ls += __shfl_down(ls, off); ld += __shfl_down(ld, off); }
            if (lane == 0){ a_s[(n0 + r) * 4 + j] = ls * LOG2E; a_d[(n0 + r) * 4 + j] = ld * LOG2E; }
        }
    }
}

// ================= single-pass edge bucketing (fixed capacity CAP per dst) =================
__global__ void k_fill(const int* __restrict__ ei, int* __restrict__ deg,
                       int* __restrict__ elist, int E, int Et)
{
    int e = blockIdx.x * blockDim.x + threadIdx.x;
    if (e >= Et) return;
    int s, d;
    if (e < E) { s = ei[e]; d = ei[E + e]; } else { s = d = e - E; }
    int slot = atomicAdd(&deg[d], 1);
    if (slot < CAP) elist[d * CAP + slot] = s;
}

// ======= GAT1 gather (wave-per-dst, 8-deep MLP) + fused GAT2 projection =======
// Logits pre-scaled by log2e -> raw exp2 for alpha.
__global__ __launch_bounds__(256) void k_gat1p2(
    const int* __restrict__ deg, const int* __restrict__ elist,
    const float* __restrict__ a_s, const float* __restrict__ a_d,
    const _Float16* __restrict__ H1, const float* __restrict__ b1,
    const float* __restrict__ W2, const float* __restrict__ as2, const float* __restrict__ ad2,
    _Float16* __restrict__ H2, float* __restrict__ a2s, float* __restrict__ a2d)
{
    __shared__ float sh2[16][264];   // 16.9 KB
    const int tid = threadIdx.x;
    const int n0 = blockIdx.x * 16;
    const int w = tid >> 6, lane = tid & 63;
    const int h = lane >> 4;
    const uint2* H1v = (const uint2*)H1;      // row = 64 uint2
    const float4 bv = *(const float4*)(b1 + lane * 4);

    #pragma unroll 1
    for (int sub = 0; sub < 4; ++sub){
        const int d = n0 + sub * 4 + w;
        const int base = d * CAP;
        const int n_e = min(deg[d], CAP);
        const float add = a_d[d * 4 + h];

        float acc0 = 0.f, acc1 = 0.f, acc2 = 0.f, acc3 = 0.f, asum = 0.f;
        int e = 0;
        for (; e + 8 <= n_e; e += 8) {        // 8 independent load chains in flight
            int s0 = elist[base + e],     s1 = elist[base + e + 1];
            int s2 = elist[base + e + 2], s3 = elist[base + e + 3];
            int s4 = elist[base + e + 4], s5 = elist[base + e + 5];
            int s6 = elist[base + e + 6], s7 = elist[base + e + 7];
            float A0 = a_s[s0 * 4 + h] + add, A1 = a_s[s1 * 4 + h] + add;
            float A2 = a_s[s2 * 4 + h] + add, A3 = a_s[s3 * 4 + h] + add;
            float A4 = a_s[s4 * 4 + h] + add, A5 = a_s[s5 * 4 + h] + add;
            float A6 = a_s[s6 * 4 + h] + add, A7 = a_s[s7 * 4 + h] + add;
            uint2 u0 = H1v[(size_t)s0 * 64 + lane], u1 = H1v[(size_t)s1 * 64 + lane];
            uint2 u2 = H1v[(size_t)s2 * 64 + lane], u3 = H1v[(size_t)s3 * 64 + lane];
            uint2 u4 = H1v[(size_t)s4 * 64 + lane], u5 = H1v[(size_t)s5 * 64 + lane];
            uint2 u6 = H1v[(size_t)s6 * 64 + lane], u7 = H1v[(size_t)s7 * 64 + lane];
            float l0 = A0 > 0.f ? A0 : NEG * A0, l1 = A1 > 0.f ? A1 : NEG * A1;
            float l2 = A2 > 0.f ? A2 : NEG * A2, l3 = A3 > 0.f ? A3 : NEG * A3;
            float l4 = A4 > 0.f ? A4 : NEG * A4, l5 = A5 > 0.f ? A5 : NEG * A5;
            float l6 = A6 > 0.f ? A6 : NEG * A6, l7 = A7 > 0.f ? A7 : NEG * A7;
            float al0 = __builtin_amdgcn_exp2f(l0), al1 = __builtin_amdgcn_exp2f(l1);
            float al2 = __builtin_amdgcn_exp2f(l2), al3 = __builtin_amdgcn_exp2f(l3);
            float al4 = __builtin_amdgcn_exp2f(l4), al5 = __builtin_amdgcn_exp2f(l5);
            float al6 = __builtin_amdgcn_exp2f(l6), al7 = __builtin_amdgcn_exp2f(l7);
            acc0 += al0*f16lo(u0.x) + al1*f16lo(u1.x) + al2*f16lo(u2.x) + al3*f16lo(u3.x)
                  + al4*f16lo(u4.x) + al5*f16lo(u5.x) + al6*f16lo(u6.x) + al7*f16lo(u7.x);
            acc1 += al0*f16hi(u0.x) + al1*f16hi(u1.x) + al2*f16hi(u2.x) + al3*f16hi(u3.x)
                  + al4*f16hi(u4.x) + al5*f16hi(u5.x) + al6*f16hi(u6.x) + al7*f16hi(u7.x);
            acc2 += al0*f16lo(u0.y) + al1*f16lo(u1.y) + al2*f16lo(u2.y) + al3*f16lo(u3.y)
                  + al4*f16lo(u4.y) + al5*f16lo(u5.y) + al6*f16lo(u6.y) + al7*f16lo(u7.y);
            acc3 += al0*f16hi(u0.y) + al1*f16hi(u1.y) + al2*f16hi(u2.y) + al3*f16hi(u3.y)
                  + al4*f16hi(u4.y) + al5*f16hi(u5.y) + al6*f16hi(u6.y) + al7*f16hi(u7.y);
            asum += al0 + al1 + al2 + al3 + al4 + al5 + al6 + al7;
        }
        for (; e + 4 <= n_e; e += 4) {
            int s0 = elist[base + e],     s1 = elist[base + e + 1];
            int s2 = elist[base + e + 2], s3 = elist[base + e + 3];
            float A0 = a_s[s0 * 4 + h] + add, A1 = a_s[s1 * 4 + h] + add;
            float A2 = a_s[s2 * 4 + h] + add, A3 = a_s[s3 * 4 + h] + add;
            uint2 u0 = H1v[(size_t)s0 * 64 + lane], u1 = H1v[(size_t)s1 * 64 + lane];
            uint2 u2 = H1v[(size_t)s2 * 64 + lane], u3 = H1v[(size_t)s3 * 64 + lane];
            float l0 = A0 > 0.f ? A0 : NEG * A0, l1 = A1 > 0.f ? A1 : NEG * A1;
            float l2 = A2 > 0.f ? A2 : NEG * A2, l3 = A3 > 0.f ? A3 : NEG * A3;
            float al0 = __builtin_amdgcn_exp2f(l0), al1 = __builtin_amdgcn_exp2f(l1);
            float al2 = __builtin_amdgcn_exp2f(l2), al3 = __builtin_amdgcn_exp2f(l3);
            acc0 += al0*f16lo(u0.x) + al1*f16lo(u1.x) + al2*f16lo(u2.x) + al3*f16lo(u3.x);
            acc1 += al0*f16hi(u0.x) + al1*f16hi(u1.x) + al2*f16hi(u2.x) + al3*f16hi(u3.x);
            acc2 += al0*f16lo(u0.y) + al1*f16lo(u1.y) + al2*f16lo(u2.y) + al3*f16lo(u3.y);
            acc3 += al0*f16hi(u0.y) + al1*f16hi(u1.y) + al2*f16hi(u2.y) + al3*f16hi(u3.y);
            asum += al0 + al1 + al2 + al3;
        }
        for (; e < n_e; ++e) {
            int s0 = elist[base + e];
            float A0 = a_s[s0 * 4 + h] + add;
            uint2 u0 = H1v[(size_t)s0 * 64 + lane];
            float l0 = A0 > 0.f ? A0 : NEG * A0;
            float al0 = __builtin_amdgcn_exp2f(l0);
            acc0 += al0 * f16lo(u0.x); acc1 += al0 * f16hi(u0.x);
            acc2 += al0 * f16lo(u0.y); acc3 += al0 * f16hi(u0.y);
            asum += al0;
        }
        const float r = __builtin_amdgcn_rcpf(asum);
        float v0 = acc0 * r + bv.x, v1 = acc1 * r + bv.y;
        float v2 = acc2 * r + bv.z, v3 = acc3 * r + bv.w;
        v0 = v0 > 0.f ? v0 : 0.f; v1 = v1 > 0.f ? v1 : 0.f;
        v2 = v2 > 0.f ? v2 : 0.f; v3 = v3 > 0.f ? v3 : 0.f;
        float4 row = {v0, v1, v2, v3};
        *(float4*)(&sh2[sub * 4 + w][lane * 4]) = row;
    }
    __syncthreads();

    // ---- gproj2 body (LDS input); a2s/a2d pre-scaled by log2e ----
    const int c = tid & 31, rg = tid >> 5;
    float a0 = 0.f, a1 = 0.f;
    for (int jj = 0; jj < 256; ++jj){
        float wv = W2[jj * 32 + c];
        a0 += sh2[rg*2][jj] * wv;
        a1 += sh2[rg*2 + 1][jj] * wv;
    }
    const float asv = as2[c], adv = ad2[c];
    H2[(size_t)(n0 + rg*2) * 32 + c]     = (_Float16)a0;
    H2[(size_t)(n0 + rg*2 + 1) * 32 + c] = (_Float16)a1;
    float s0 = a0 * asv, d0 = a0 * adv, s1 = a1 * asv, d1 = a1 * adv;
    #pragma unroll
    for (int o = 16; o >= 1; o >>= 1){
        s0 += __shfl_down(s0, o, 32); d0 += __shfl_down(d0, o, 32);
        s1 += __shfl_down(s1, o, 32); d1 += __shfl_down(d1, o, 32);
    }
    if (c == 0){
        a2s[n0 + rg*2] = s0 * LOG2E;     a2d[n0 + rg*2] = d0 * LOG2E;
        a2s[n0 + rg*2 + 1] = s1 * LOG2E; a2d[n0 + rg*2 + 1] = d1 * LOG2E;
    }
}

// ================= GAT2 gather: 4 dsts/block, 4 edges/parity in flight =================
__global__ __launch_bounds__(256) void k_gat2(
    const int* __restrict__ deg, const int* __restrict__ elist,
    const float* __restrict__ a2s, const float* __restrict__ a2d,
    const _Float16* __restrict__ H2, const float* __restrict__ b2,
    float* __restrict__ outp)
{
    const int d = blockIdx.x * 4 + (threadIdx.x >> 6);
    const int lane = threadIdx.x & 63;
    const int base = d * CAP;
    const int n_e = min(deg[d], CAP);
    const float add = a2d[d];
    const int half = lane >> 5, c = lane & 31;

    float acc = 0.f, asum = 0.f;
    int e = half;
    for (; e + 6 < n_e; e += 8) {             // 4 edges (e, e+2, e+4, e+6) per parity
        int s0 = elist[base + e],     s1 = elist[base + e + 2];
        int s2 = elist[base + e + 4], s3 = elist[base + e + 6];
        float a0 = a2s[s0] + add, a1 = a2s[s1] + add;
        float a2 = a2s[s2] + add, a3 = a2s[s3] + add;
        float h0 = (float)H2[(size_t)s0 * 32 + c], h1 = (float)H2[(size_t)s1 * 32 + c];
        float h2v = (float)H2[(size_t)s2 * 32 + c], h3 = (float)H2[(size_t)s3 * 32 + c];
        float l0 = a0 > 0.f ? a0 : NEG * a0, l1 = a1 > 0.f ? a1 : NEG * a1;
        float l2 = a2 > 0.f ? a2 : NEG * a2, l3 = a3 > 0.f ? a3 : NEG * a3;
        float al0 = __builtin_amdgcn_exp2f(l0), al1 = __builtin_amdgcn_exp2f(l1);
        float al2 = __builtin_amdgcn_exp2f(l2), al3 = __builtin_amdgcn_exp2f(l3);
        acc  += al0 * h0 + al1 * h1 + al2 * h2v + al3 * h3;
        asum += al0 + al1 + al2 + al3;
    }
    for (; e < n_e; e += 2) {
        int s0 = elist[base + e];
        float a0 = a2s[s0] + add;
        float l0 = a0 > 0.f ? a0 : NEG * a0;
        float al0 = __builtin_amdgcn_exp2f(l0);
        acc  += al0 * (float)H2[(size_t)s0 * 32 + c];
        asum += al0;
    }
    acc  += __shfl_down(acc, 32);
    asum += __shfl_down(asum, 32);
    if (lane < 32) outp[(size_t)d * 32 + c] = acc * __builtin_amdgcn_rcpf(asum) + b2[c];
}

static inline int cdiv(long long a, long long b) { return (int)((a + b - 1) / b); }

extern "C" void kernel_launch(void* const* d_in, const int* in_sizes, int n_in,
                              void* d_out, int out_size, void* d_ws, size_t ws_size,
                              hipStream_t stream)
{
    const float* x    = (const float*)d_in[0];
    const int*   ei   = (const int*)d_in[1];
    const float* Wih0 = (const float*)d_in[2];
    const float* Whh0 = (const float*)d_in[3];
    const float* bih0 = (const float*)d_in[4];
    const float* bhh0 = (const float*)d_in[5];
    const float* Wih1 = (const float*)d_in[6];
    const float* Whh1 = (const float*)d_in[7];
    const float* bih1 = (const float*)d_in[8];
    const float* bhh1 = (const float*)d_in[9];
    const float* W1   = (const float*)d_in[10];
    const float* as1  = (const float*)d_in[11];
    const float* ad1  = (const float*)d_in[12];
    const float* b1   = (const float*)d_in[13];
    const float* W2   = (const float*)d_in[14];
    const float* as2  = (const float*)d_in[15];
    const float* ad2  = (const float*)d_in[16];
    const float* b2   = (const float*)d_in[17];
    float* outp = (float*)d_out;

    const int N  = in_sizes[0] / (Tt * INP);
    const int E  = in_sizes[1] / 2;
    const int Et = E + N;

    float* ws = (float*)d_ws;
    _Float16* H1 = (_Float16*)ws;                     // slot N*128 f32 (N*256 f16)
    _Float16* H2 = (_Float16*)(ws + (size_t)N * 128); // slot N*16 f32 (N*32 f16)
    float* as1p = (float*)H2 + (size_t)N * 16;        // N*4
    float* ad1p = as1p + (size_t)N * 4;               // N*4
    float* a2s  = ad1p + (size_t)N * 4;               // N
    float* a2d  = a2s + N;                            // N
    int* deg    = (int*)(a2d + N);                    // N
    int* elist  = deg + N;                            // N*CAP

    // ---- fused 2-layer LSTM + GAT1 projection (also zero-inits deg) ----
    k_lstm_fused<<<dim3(N / 16), dim3(256), 0, stream>>>(
        x, Wih0, Whh0, bih0, bhh0, Wih1, Whh1, bih1, bhh1,
        W1, as1, ad1, H1, as1p, ad1p, deg);

    // ---- single-pass edge bucketing ----
    k_fill<<<cdiv(Et, 256), 256, 0, stream>>>(ei, deg, elist, E, Et);

    // ---- GAT1 gather + GAT2 projection (fused) ----
    k_gat1p2<<<dim3(N / 16), dim3(256), 0, stream>>>(
        deg, elist, as1p, ad1p, H1, b1, W2, as2, ad2, H2, a2s, a2d);

    // ---- GAT2 gather ----
    k_gat2<<<dim3(N / 4), dim3(256), 0, stream>>>(deg, elist, a2s, a2d, H2, b2, outp);
}